// Round 11
// baseline (605.274 us; speedup 1.0000x reference)
//
#include <hip/hip_runtime.h>
#include <hip/hip_bf16.h>

// GGCN: g1=relu(A@(x@W1)+b1); g2=relu(A@(g1@W2)+b2); out=relu(g2@Wd1+bd1)@Wd2+bd2
// N=16384, F=32, H=64, A dense f32 (1.07 GB, read 2x -> HBM floor ~341us).
// R11: CLEAN 512B-granule test. Wave owns 32 rows x K-half; K-step 128 ->
// each A load instruction = 4 rows x 512B CONTIGUOUS (page locality).
// B-frags: ONCE per tile into regs from L2-resident Ht (not per-MFMA - R10's
// mistake). Wave-private everything, ZERO barriers. 64KB LDS -> 2 blocks/CU
// (2 waves/SIMD, 2x R6 occupancy). Grid 256 = 128 rowblks x 2 K-halves;
// kh=(bid>>2)&1 constant per XCD residue -> 1MB Ht half per XCD L2.
// Partials gP[2] + R7's proven reduce kernel.

typedef __bf16 bf16x8 __attribute__((ext_vector_type(8)));
typedef float  f32x16 __attribute__((ext_vector_type(16)));
typedef float  f32x4v __attribute__((ext_vector_type(4)));
typedef int    i32x4  __attribute__((ext_vector_type(4)));

#define NNODE 16384
#define KDIM  16384
#define HCOL  64

__device__ inline i32x4 pack8(f32x4v a, f32x4v b){
  bf16x8 t;
  t[0]=(__bf16)a[0]; t[1]=(__bf16)a[1]; t[2]=(__bf16)a[2]; t[3]=(__bf16)a[3];
  t[4]=(__bf16)b[0]; t[5]=(__bf16)b[1]; t[6]=(__bf16)b[2]; t[7]=(__bf16)b[3];
  return __builtin_bit_cast(i32x4, t);
}
#define BC(x) __builtin_bit_cast(bf16x8, x)

// ---------------- big kernel: gP[kh] = A[rows, kh-half] @ Ht^T ----------------
// block = 256 thr = 4 waves x 32-row strips. Tile = 32 rows x 128 k. 64 tiles.
// LDS: per (wave,buf) 32 rows x 16 chunks(16B) = 8 KB -> 64 KB total.
__global__ __launch_bounds__(256, 2) void gcn_layer_kernel(
    const float* __restrict__ A,      // [16384][16384] f32
    const __bf16* __restrict__ Ht,    // [64][16384] bf16 (transposed H)
    float* __restrict__ gP)           // [2][16384][64] f32 partials
{
  __shared__ i32x4 sA[4*2*512];       // (wid,buf) x 32 rows x 16 chunks

  const int tid  = threadIdx.x;
  const int lane = tid & 63;
  const int wid  = tid >> 6;              // 0..3: 32-row strip
  const int bid  = blockIdx.x;
  const int kh   = (bid >> 2) & 1;        // constant per bid%8 -> per-XCD Ht half
  const int rowblk = (bid & 3) | ((bid >> 3) << 2);   // bijective 0..127
  const int row0 = rowblk * 128 + wid * 32;

  const int srow = lane >> 4;             // 0..3 staging row-in-group
  const int scol = lane & 15;             // lane's 32B f32 slot (16 per 512B)
  const int r    = lane & 31;
  const int hsub = lane >> 5;             // 8-k half of the 16-k MFMA window
  const int x15  = r & 15;

  const size_t k0 = (size_t)kh * 8192;

  f32x4v ra[16];                          // A staging (one tile: 32 rows x 512B)
  i32x4  rb0[8], rb1[8];                  // B frags for one tile (regs, from L2)

  const float*  pA0 = A  + (size_t)(row0 + srow) * KDIM + k0 + (size_t)scol * 8;
  const __bf16* pB0 = Ht + (size_t)r        * KDIM + k0 + (size_t)hsub * 8;
  const __bf16* pB1 = pB0 + (size_t)32 * KDIM;

  auto stage_load = [&](int t){           // 16 loads, each 4 rows x 512B contig
    const float* p = pA0 + (size_t)t * 128;
    #pragma unroll
    for (int gg = 0; gg < 8; ++gg){       // rows gg*4 + srow
      const float* q = p + (size_t)gg * 4 * KDIM;
      ra[2*gg]   = __builtin_nontemporal_load((const f32x4v*)q);      // A: stream
      ra[2*gg+1] = __builtin_nontemporal_load((const f32x4v*)(q + 4));
    }
  };

  auto stage_write = [&](int buf){
    i32x4* dA = &sA[(wid*2 + buf) * 512];
    #pragma unroll
    for (int gg = 0; gg < 8; ++gg){
      int row = gg*4 + srow;
      dA[row*16 + (scol ^ (row & 15))] = pack8(ra[2*gg], ra[2*gg+1]);
    }
  };

  auto loadB = [&](int t){                // once per tile, 16B/lane, L2-resident
    const __bf16* q0 = pB0 + (size_t)t * 128;
    const __bf16* q1 = pB1 + (size_t)t * 128;
    #pragma unroll
    for (int kk = 0; kk < 8; ++kk){
      rb0[kk] = *(const i32x4*)(q0 + kk*16);
      rb1[kk] = *(const i32x4*)(q1 + kk*16);
    }
  };

  f32x16 acc0 = {}, acc1 = {};

  auto compute = [&](int buf, int t){
    loadB(t);                             // issued first; ds_reads overlap
    const i32x4* bA = &sA[(wid*2 + buf) * 512];
    #pragma unroll
    for (int kk = 0; kk < 8; ++kk){
      int c = (kk*2 + hsub) ^ x15;
      bf16x8 a0 = BC(bA[r*16 + c]);
      acc0 = __builtin_amdgcn_mfma_f32_32x32x16_bf16(a0, BC(rb0[kk]), acc0, 0,0,0);
      acc1 = __builtin_amdgcn_mfma_f32_32x32x16_bf16(a0, BC(rb1[kk]), acc1, 0,0,0);
    }
  };

  // barrier-free per-wave dbuf pipeline over 64 tiles (K-half, 128 k each)
  stage_load(0);
  stage_write(0);
  stage_load(1);
  #pragma unroll 1
  for (int t = 0; t < 63; ++t){
    compute(t & 1, t);
    stage_write((t+1) & 1);
    if (t < 62) stage_load(t + 2);
  }
  compute(1, 63);

  // epilogue: store this wave's 32x64 partial (wave-private rows, no sync)
  float* out = gP + ((size_t)kh * NNODE + row0) * HCOL;
  #pragma unroll
  for (int j = 0; j < 16; ++j){
    int rr = (j&3) + 8*(j>>2) + 4*hsub;   // C/D layout [verified R1..R10]
    out[(size_t)rr * HCOL + r]      = acc0[j];
    out[(size_t)rr * HCOL + 32 + r] = acc1[j];
  }
}

// ---------------- reduce: g = relu(gP[0] + gP[1] + bias) ----------------
__global__ __launch_bounds__(256) void reduce_kernel(
    const float* __restrict__ gP,    // [2][16384][64]
    const float* __restrict__ bias,  // [64]
    float* __restrict__ g)           // [16384][64]
{
  const size_t i = (size_t)blockIdx.x * 256 + threadIdx.x;   // f32x4 index
  const f32x4v* p = (const f32x4v*)gP;
  f32x4v s = p[i] + p[i + 262144];
  f32x4v b = *(const f32x4v*)(bias + (i & 15) * 4);
  f32x4v o;
  o[0] = fmaxf(s[0] + b[0], 0.f);
  o[1] = fmaxf(s[1] + b[1], 0.f);
  o[2] = fmaxf(s[2] + b[2], 0.f);
  o[3] = fmaxf(s[3] + b[3], 0.f);
  ((f32x4v*)g)[i] = o;
}

// ---------------- projection: out[h][n] = sum_f in[n][f]*W[f][h], bf16 out ----------------
template<int F>
__global__ __launch_bounds__(128) void proj_T_kernel(
    const float* __restrict__ in,   // [N][F]
    const float* __restrict__ W,    // [F][64]
    __bf16* __restrict__ out)       // [64][N]
{
  constexpr int FP = F + 4;
  __shared__ float sWt[64*FP];
  __shared__ short sOut[64*136];

  int tid = threadIdx.x;
  for (int e = tid; e < 64*F; e += 128){
    int h = e / F, j = e - h*F;
    sWt[h*FP + j] = W[j*64 + h];
  }
  __syncthreads();

  const size_t n = (size_t)blockIdx.x*128 + tid;
  float rowv[F];
  #pragma unroll
  for (int j=0; j<F; j+=4){
    f32x4v v = *(const f32x4v*)(in + n*F + j);
    rowv[j]=v[0]; rowv[j+1]=v[1]; rowv[j+2]=v[2]; rowv[j+3]=v[3];
  }
  #pragma unroll
  for (int h=0; h<64; ++h){
    float s = 0.f;
    #pragma unroll
    for (int j=0; j<F; j+=4){
      f32x4v w = *(const f32x4v*)&sWt[h*FP + j];
      s += rowv[j]*w[0] + rowv[j+1]*w[1] + rowv[j+2]*w[2] + rowv[j+3]*w[3];
    }
    sOut[h*136 + tid] = __builtin_bit_cast(short, (__bf16)s);
  }
  __syncthreads();

  const size_t n0 = (size_t)blockIdx.x*128;
  #pragma unroll
  for (int pi=0; pi<8; ++pi){
    int p = pi*128 + tid;
    int h = p >> 4, cc = p & 15;
    i32x4 v = *(const i32x4*)&sOut[h*136 + cc*8];
    *(i32x4*)(out + (size_t)h*NNODE + n0 + cc*8) = v;
  }
}

// ---------------- tail MLP: out[n] = relu(g2[n]@Wd1+bd1)@Wd2 + bd2 ----------------
__global__ __launch_bounds__(256) void tail_kernel(
    const float* __restrict__ g2,
    const float* __restrict__ Wd1,
    const float* __restrict__ bd1,
    const float* __restrict__ Wd2,
    const float* __restrict__ bd2,
    float* __restrict__ outp)
{
  __shared__ float sW[64*32];
  __shared__ float sb1[32], sw2[32];
  int tid = threadIdx.x;
  for (int e=tid; e<2048; e+=256) sW[e] = Wd1[e];
  if (tid < 32){ sb1[tid] = bd1[tid]; sw2[tid] = Wd2[tid]; }
  __syncthreads();

  size_t n = (size_t)blockIdx.x*256 + tid;
  float rv[64];
  #pragma unroll
  for (int j=0;j<64;j+=4){
    f32x4v v = *(const f32x4v*)(g2 + n*64 + j);
    rv[j]=v[0]; rv[j+1]=v[1]; rv[j+2]=v[2]; rv[j+3]=v[3];
  }
  float o = 0.f;
  #pragma unroll
  for (int c=0;c<32;++c){
    float s = sb1[c];
    #pragma unroll
    for (int j=0;j<64;++j) s += rv[j]*sW[j*32 + c];
    o += fmaxf(s, 0.f) * sw2[c];
  }
  outp[n] = o + bd2[0];
}

extern "C" void kernel_launch(void* const* d_in, const int* in_sizes, int n_in,
                              void* d_out, int out_size, void* d_ws, size_t ws_size,
                              hipStream_t stream)
{
  const float* x   = (const float*)d_in[0];
  const float* a   = (const float*)d_in[1];
  const float* W1  = (const float*)d_in[2];
  const float* b1  = (const float*)d_in[3];
  const float* W2  = (const float*)d_in[4];
  const float* b2  = (const float*)d_in[5];
  const float* Wd1 = (const float*)d_in[6];
  const float* bd1 = (const float*)d_in[7];
  const float* Wd2 = (const float*)d_in[8];
  const float* bd2 = (const float*)d_in[9];
  float* outp = (float*)d_out;

  char* ws = (char*)d_ws;                       // needs 20 MB
  __bf16* Ht1 = (__bf16*)(ws);                  // [64][16384] bf16, 2 MB
  __bf16* Ht2 = (__bf16*)(ws + (2u<<20));       // 2 MB
  float*  g1  = (float*)(ws + (4u<<20));        // [16384][64] f32, 4 MB
  float*  g2  = (float*)(ws + (8u<<20));        // 4 MB
  float*  gP  = (float*)(ws + (12u<<20));       // [2][16384][64] f32, 8 MB

  proj_T_kernel<32><<<128, 128, 0, stream>>>(x,  W1, Ht1);
  gcn_layer_kernel <<<256, 256, 0, stream>>>(a, Ht1, gP);
  reduce_kernel    <<<1024, 256, 0, stream>>>(gP, b1, g1);
  proj_T_kernel<64><<<128, 128, 0, stream>>>(g1, W2, Ht2);
  gcn_layer_kernel <<<256, 256, 0, stream>>>(a, Ht2, gP);
  reduce_kernel    <<<1024, 256, 0, stream>>>(gP, b2, g2);
  tail_kernel      <<<64, 256, 0, stream>>>(g2, Wd1, bd1, Wd2, bd2, outp);
}

// Round 12
// 425.960 us; speedup vs baseline: 1.4210x; 1.4210x over previous
//
#include <hip/hip_runtime.h>
#include <hip/hip_bf16.h>

// GGCN: g1=relu(A@(x@W1)+b1); g2=relu(A@(g1@W2)+b2); out=relu(g2@Wd1+bd1)@Wd2+bd2
// N=16384, F=32, H=64, A dense f32 (1.07 GB, read 2x -> HBM floor ~341us).
// R12 = R6 (best, 453.8us) with ONE change: A loads are PLAIN (no nontemporal).
// Theory: R6's two 16B/lane loads split a 32B/lane footprint; with nt the
// partner 16B of each 64B line may re-fetch from DRAM (evict-first defeats the
// guaranteed L2 hit), inflating effective A traffic. Clean single-variable A/B.

typedef __bf16 bf16x8 __attribute__((ext_vector_type(8)));
typedef float  f32x16 __attribute__((ext_vector_type(16)));
typedef float  f32x4v __attribute__((ext_vector_type(4)));
typedef int    i32x4  __attribute__((ext_vector_type(4)));

#define NNODE 16384
#define KDIM  16384
#define HCOL  64

__device__ inline i32x4 pack8(f32x4v a, f32x4v b){
  bf16x8 t;
  t[0]=(__bf16)a[0]; t[1]=(__bf16)a[1]; t[2]=(__bf16)a[2]; t[3]=(__bf16)a[3];
  t[4]=(__bf16)b[0]; t[5]=(__bf16)b[1]; t[6]=(__bf16)b[2]; t[7]=(__bf16)b[3];
  return __builtin_bit_cast(i32x4, t);
}
#define BC(x) __builtin_bit_cast(bf16x8, x)

// ---------------- big kernel: G = relu(A @ Ht^T + bias) ----------------
// block = 256 thr (4 waves). BM=64 rows. wave kw owns K-quarter kw (wave-private
// LDS dbuf, no main-loop barriers). XOR swizzle on 16B chunks: c ^ (row&7).
__global__ __launch_bounds__(256, 1) void gcn_layer_kernel(
    const float* __restrict__ A,      // [16384][16384] f32
    const __bf16* __restrict__ Ht,    // [64][16384] bf16 (transposed H)
    const float* __restrict__ bias,   // [64]
    float* __restrict__ G)            // [16384][64] f32
{
  __shared__ i32x4 sA[4*2*512];   // (kw,buf) x 64 rows x 8 chunks = 64 KB
  __shared__ i32x4 sH[4*2*512];   // (kw,buf) x 64 rows x 8 chunks = 64 KB

  const int tid  = threadIdx.x;
  const int lane = tid & 63;
  const int kw   = tid >> 6;          // K-quarter 0..3
  const int row0 = blockIdx.x * 64;

  const int rA0  = lane >> 3;         // 0..7 staging row-in-group
  const int ccA  = lane & 7;          // staging logical 16B chunk (of 8 per 64k)
  const int swzA = ccA ^ rA0;         // row&7 == rA0 for all staged rows
  const int r    = lane & 31;
  const int hsub = lane >> 5;         // 0/1 k-subgroup within 16-k window
  const int xs   = r & 7;

  const size_t k0 = (size_t)kw * 4096;

  f32x4v ra[16]; i32x4 rh[8];

  const float* pA0 = A + (size_t)(row0 + rA0) * KDIM + k0 + (size_t)ccA*8;
  const i32x4* pH0 = (const i32x4*)Ht + (size_t)rA0 * (KDIM/8) + k0/8 + ccA;

  auto stage_load = [&](int t){
    const float* pA = pA0 + (size_t)t*64;
    #pragma unroll
    for (int pi=0; pi<8; ++pi){                    // rows rA0 + pi*8 (64 rows)
      const float* p = pA + (size_t)pi*8*KDIM;
      ra[2*pi]   = *(const f32x4v*)p;              // A: PLAIN loads (R12 change)
      ra[2*pi+1] = *(const f32x4v*)(p+4);
    }
    const i32x4* pH = pH0 + (size_t)t*8;
    #pragma unroll
    for (int pi=0; pi<8; ++pi)
      rh[pi] = pH[(size_t)pi*8*(KDIM/8)];          // Ht: keep L2-cached
  };

  auto stage_write = [&](int buf){
    i32x4* dA = &sA[(kw*2+buf)*512];
    #pragma unroll
    for (int pi=0; pi<8; ++pi)
      dA[(rA0 + pi*8)*8 + swzA] = pack8(ra[2*pi], ra[2*pi+1]);
    i32x4* dH = &sH[(kw*2+buf)*512];
    #pragma unroll
    for (int pi=0; pi<8; ++pi)
      dH[(rA0 + pi*8)*8 + swzA] = rh[pi];
  };

  f32x16 acc00 = {}, acc01 = {}, acc10 = {}, acc11 = {};

  auto compute = [&](int buf){
    const i32x4* bA = &sA[(kw*2+buf)*512];
    const i32x4* bH = &sH[(kw*2+buf)*512];
    #pragma unroll
    for (int kk=0; kk<4; ++kk){
      int c = (kk*2 + hsub) ^ xs;                  // (r+32)&7 == r&7 -> same c
      bf16x8 a0 = BC(bA[r*8 + c]);
      bf16x8 a1 = BC(bA[(r+32)*8 + c]);
      bf16x8 b0 = BC(bH[r*8 + c]);
      bf16x8 b1 = BC(bH[(r+32)*8 + c]);
      acc00 = __builtin_amdgcn_mfma_f32_32x32x16_bf16(a0, b0, acc00, 0,0,0);
      acc01 = __builtin_amdgcn_mfma_f32_32x32x16_bf16(a0, b1, acc01, 0,0,0);
      acc10 = __builtin_amdgcn_mfma_f32_32x32x16_bf16(a1, b0, acc10, 0,0,0);
      acc11 = __builtin_amdgcn_mfma_f32_32x32x16_bf16(a1, b1, acc11, 0,0,0);
    }
  };

  // barrier-free per-wave pipeline over 64 tiles (k-quarter, 64 k each)
  stage_load(0);
  stage_write(0);
  stage_load(1);
  #pragma unroll 1
  for (int t=0; t<63; ++t){
    compute(t&1);
    stage_write((t+1)&1);
    if (t < 62) stage_load(t+2);
  }
  compute(1);                  // tile 63

  __syncthreads();             // red aliases kw0..2's sA regions

  // split-K=4 reduce: waves 1..3 dump partials, wave 0 combines
  float* red = (float*)sA;     // 3 x 64x64 f32 = 48 KB
  if (kw > 0){
    float* rd = red + (size_t)(kw-1)*4096;
    #pragma unroll
    for (int j=0; j<16; ++j){
      int rr = (j&3) + 8*(j>>2) + 4*hsub;          // C/D layout [verified R1..R11]
      rd[(rr   )*64 + r]      = acc00[j];
      rd[(rr   )*64 + 32 + r] = acc01[j];
      rd[(rr+32)*64 + r]      = acc10[j];
      rd[(rr+32)*64 + 32 + r] = acc11[j];
    }
  }
  __syncthreads();
  if (kw == 0){
    #pragma unroll
    for (int j=0; j<16; ++j){
      int rr = (j&3) + 8*(j>>2) + 4*hsub;
      float v00 = acc00[j] + red[(rr   )*64+r]    + red[4096+(rr   )*64+r]    + red[8192+(rr   )*64+r]    + bias[r];
      float v01 = acc01[j] + red[(rr   )*64+32+r] + red[4096+(rr   )*64+32+r] + red[8192+(rr   )*64+32+r] + bias[32+r];
      float v10 = acc10[j] + red[(rr+32)*64+r]    + red[4096+(rr+32)*64+r]    + red[8192+(rr+32)*64+r]    + bias[r];
      float v11 = acc11[j] + red[(rr+32)*64+32+r] + red[4096+(rr+32)*64+32+r] + red[8192+(rr+32)*64+32+r] + bias[32+r];
      G[(size_t)(row0 + rr     )*HCOL + r]      = fmaxf(v00, 0.f);
      G[(size_t)(row0 + rr     )*HCOL + 32 + r] = fmaxf(v01, 0.f);
      G[(size_t)(row0 + rr + 32)*HCOL + r]      = fmaxf(v10, 0.f);
      G[(size_t)(row0 + rr + 32)*HCOL + 32 + r] = fmaxf(v11, 0.f);
    }
  }
}

// ---------------- projection: out[h][n] = sum_f in[n][f]*W[f][h], bf16 out ----------------
template<int F>
__global__ __launch_bounds__(128) void proj_T_kernel(
    const float* __restrict__ in,   // [N][F]
    const float* __restrict__ W,    // [F][64]
    __bf16* __restrict__ out)       // [64][N]
{
  constexpr int FP = F + 4;
  __shared__ float sWt[64*FP];
  __shared__ short sOut[64*136];

  int tid = threadIdx.x;
  for (int e = tid; e < 64*F; e += 128){
    int h = e / F, j = e - h*F;
    sWt[h*FP + j] = W[j*64 + h];
  }
  __syncthreads();

  const size_t n = (size_t)blockIdx.x*128 + tid;
  float rowv[F];
  #pragma unroll
  for (int j=0; j<F; j+=4){
    f32x4v v = *(const f32x4v*)(in + n*F + j);
    rowv[j]=v[0]; rowv[j+1]=v[1]; rowv[j+2]=v[2]; rowv[j+3]=v[3];
  }
  #pragma unroll
  for (int h=0; h<64; ++h){
    float s = 0.f;
    #pragma unroll
    for (int j=0; j<F; j+=4){
      f32x4v w = *(const f32x4v*)&sWt[h*FP + j];
      s += rowv[j]*w[0] + rowv[j+1]*w[1] + rowv[j+2]*w[2] + rowv[j+3]*w[3];
    }
    sOut[h*136 + tid] = __builtin_bit_cast(short, (__bf16)s);
  }
  __syncthreads();

  const size_t n0 = (size_t)blockIdx.x*128;
  #pragma unroll
  for (int pi=0; pi<8; ++pi){
    int p = pi*128 + tid;
    int h = p >> 4, cc = p & 15;
    i32x4 v = *(const i32x4*)&sOut[h*136 + cc*8];
    *(i32x4*)(out + (size_t)h*NNODE + n0 + cc*8) = v;
  }
}

// ---------------- tail MLP: out[n] = relu(g2[n]@Wd1+bd1)@Wd2 + bd2 ----------------
__global__ __launch_bounds__(256) void tail_kernel(
    const float* __restrict__ g2,
    const float* __restrict__ Wd1,
    const float* __restrict__ bd1,
    const float* __restrict__ Wd2,
    const float* __restrict__ bd2,
    float* __restrict__ outp)
{
  __shared__ float sW[64*32];
  __shared__ float sb1[32], sw2[32];
  int tid = threadIdx.x;
  for (int e=tid; e<2048; e+=256) sW[e] = Wd1[e];
  if (tid < 32){ sb1[tid] = bd1[tid]; sw2[tid] = Wd2[tid]; }
  __syncthreads();

  size_t n = (size_t)blockIdx.x*256 + tid;
  float rv[64];
  #pragma unroll
  for (int j=0;j<64;j+=4){
    f32x4v v = *(const f32x4v*)(g2 + n*64 + j);
    rv[j]=v[0]; rv[j+1]=v[1]; rv[j+2]=v[2]; rv[j+3]=v[3];
  }
  float o = 0.f;
  #pragma unroll
  for (int c=0;c<32;++c){
    float s = sb1[c];
    #pragma unroll
    for (int j=0;j<64;++j) s += rv[j]*sW[j*32 + c];
    o += fmaxf(s, 0.f) * sw2[c];
  }
  outp[n] = o + bd2[0];
}

extern "C" void kernel_launch(void* const* d_in, const int* in_sizes, int n_in,
                              void* d_out, int out_size, void* d_ws, size_t ws_size,
                              hipStream_t stream)
{
  const float* x   = (const float*)d_in[0];
  const float* a   = (const float*)d_in[1];
  const float* W1  = (const float*)d_in[2];
  const float* b1  = (const float*)d_in[3];
  const float* W2  = (const float*)d_in[4];
  const float* b2  = (const float*)d_in[5];
  const float* Wd1 = (const float*)d_in[6];
  const float* bd1 = (const float*)d_in[7];
  const float* Wd2 = (const float*)d_in[8];
  const float* bd2 = (const float*)d_in[9];
  float* outp = (float*)d_out;

  char* ws = (char*)d_ws;                       // needs 12 MB
  __bf16* Ht1 = (__bf16*)(ws);                  // [64][16384] bf16, 2 MB
  __bf16* Ht2 = (__bf16*)(ws + (2u<<20));       // 2 MB
  float*  g1  = (float*)(ws + (4u<<20));        // [16384][64] f32, 4 MB
  float*  g2  = (float*)(ws + (8u<<20));        // 4 MB

  proj_T_kernel<32><<<128, 128, 0, stream>>>(x,  W1, Ht1);
  gcn_layer_kernel <<<256, 256, 0, stream>>>(a, Ht1, b1, g1);
  proj_T_kernel<64><<<128, 128, 0, stream>>>(g1, W2, Ht2);
  gcn_layer_kernel <<<256, 256, 0, stream>>>(a, Ht2, b2, g2);
  tail_kernel      <<<64, 256, 0, stream>>>(g2, Wd1, bd1, Wd2, bd2, outp);
}